// Round 10
// baseline (371.532 us; speedup 1.0000x reference)
//
#include <hip/hip_runtime.h>
#include <cstdint>
#include <cstddef>

#define IN_CH 768
#define FH 14
#define FW 14
#define NPOS 196         // 14*14
#define NA 9
#define NANCH 1764       // 196*9
#define K1 1000
#define TOPK_N 300
#define CSPLIT 16
#define CPBLK (IN_CH / CSPLIT)  // 48 channels per block
#define WCH (CPBLK / 4)         // 12 channels per wave
#define HQ 8                    // heads split-C chunks
#define HCC (IN_CH / HQ)        // 96 channels per chunk
#define BBOX_CLIP 4.135166556742356f
#define IMG_W 224.0f
#define IMG_H 224.0f

typedef unsigned long long ull;

// ---------- helpers ----------
__device__ __forceinline__ uint32_t f2sort(float f) {
    uint32_t b = __float_as_uint(f);
    return (b & 0x80000000u) ? ~b : (b | 0x80000000u);
}
__device__ __forceinline__ float sort2f(uint32_t s) {
    uint32_t b = (s & 0x80000000u) ? (s & 0x7fffffffu) : ~s;
    return __uint_as_float(b);
}
__device__ __forceinline__ ull readlane_u64(ull v, int l) {
    unsigned lo = __builtin_amdgcn_readlane((unsigned)(v & 0xffffffffull), l);
    unsigned hi = __builtin_amdgcn_readlane((unsigned)(v >> 32), l);
    return ((ull)hi << 32) | (ull)lo;
}

// ---------- kernel 0: zero-padded 16x16 feature planes ----------
__global__ __launch_bounds__(256) void k_pad(const float* __restrict__ feature,
                                             float* __restrict__ pad) {
    const int c = blockIdx.x, t = threadIdx.x;
    const int row = t >> 4, col = t & 15;
    const bool in = (row >= 1 && row <= 14 && col >= 1 && col <= 14);
    pad[(size_t)c * 256 + t] = in ? feature[IN_CH + (size_t)c * NPOS + (row - 1) * FW + (col - 1)] : 0.f;
}

// ---------- kernel 1: 3x3 conv, 1x4 strips, aligned vector taps ----------
__global__ __launch_bounds__(256) void k_conv(const float* __restrict__ pad,
                                              const float* __restrict__ w_conv,
                                              float* __restrict__ xpart) {
    __shared__ float wlds[CPBLK * 8 * 12];   // 18,432 B
    __shared__ float redbuf[8 * NPOS];       // 6,272 B
    const int tid  = threadIdx.x;
    const int wv   = tid >> 6, lane = tid & 63;
    const int cs   = blockIdx.x & (CSPLIT - 1);
    const int ob   = blockIdx.x / CSPLIT;
    const int o0   = ob * 8;

    for (int i = tid; i < CPBLK * 8 * 9; i += 256) {
        const int oo = i / (CPBLK * 9);
        const int r  = i % (CPBLK * 9);
        const int cc = r / 9, k = r % 9;
        wlds[(cc * 8 + oo) * 12 + k] =
            w_conv[((size_t)(o0 + oo) * IN_CH + (cs * CPBLK + cc)) * 9 + k];
    }

    const int row = lane >> 2, s4 = (lane & 3) * 4;
    const bool act = (row < FH);
    const int rr = act ? row : 0;

    const int cbase = cs * CPBLK + wv * WCH;
    const float* base = pad + (size_t)cbase * 256 + rr * 16 + s4;

    float acc[8][4];
#pragma unroll
    for (int oo = 0; oo < 8; oo++)
#pragma unroll
        for (int q = 0; q < 4; q++) acc[oo][q] = 0.f;

    float t[3][6];
#pragma unroll
    for (int rI = 0; rI < 3; rI++) {
        const float4 a = *(const float4*)(base + rI * 16);
        const float2 b = *(const float2*)(base + rI * 16 + 4);
        t[rI][0] = a.x; t[rI][1] = a.y; t[rI][2] = a.z; t[rI][3] = a.w;
        t[rI][4] = b.x; t[rI][5] = b.y;
    }

    __syncthreads();   // weights staged

    for (int cc = 0; cc < WCH; cc++) {
        float tn[3][6];
        if (cc + 1 < WCH) {
            const float* nb = base + (size_t)(cc + 1) * 256;
#pragma unroll
            for (int rI = 0; rI < 3; rI++) {
                const float4 a = *(const float4*)(nb + rI * 16);
                const float2 b = *(const float2*)(nb + rI * 16 + 4);
                tn[rI][0] = a.x; tn[rI][1] = a.y; tn[rI][2] = a.z; tn[rI][3] = a.w;
                tn[rI][4] = b.x; tn[rI][5] = b.y;
            }
        }
        const int cib = wv * WCH + cc;
#pragma unroll
        for (int oo = 0; oo < 8; oo++) {
            const int off = (cib * 8 + oo) * 12;
            const float4 wA = *(const float4*)&wlds[off];
            const float4 wB = *(const float4*)&wlds[off + 4];
            const float  w8 = wlds[off + 8];
#pragma unroll
            for (int k = 0; k < 4; k++) {
                acc[oo][k] += t[0][k] * wA.x + t[0][k + 1] * wA.y + t[0][k + 2] * wA.z
                            + t[1][k] * wA.w + t[1][k + 1] * wB.x + t[1][k + 2] * wB.y
                            + t[2][k] * wB.z + t[2][k + 1] * wB.w + t[2][k + 2] * w8;
            }
        }
        if (cc + 1 < WCH) {
#pragma unroll
            for (int rI = 0; rI < 3; rI++)
#pragma unroll
                for (int j = 0; j < 6; j++) t[rI][j] = tn[rI][j];
        }
    }

    __syncthreads();
    for (int w = 0; w < 4; w++) {
        if (wv == w && act) {
#pragma unroll
            for (int oo = 0; oo < 8; oo++)
#pragma unroll
                for (int k = 0; k < 4; k++) {
                    const int cx = s4 + k;
                    if (cx < FW) {
                        const int p = row * FW + cx;
                        if (w == 0) redbuf[oo * NPOS + p] = acc[oo][k];
                        else        redbuf[oo * NPOS + p] += acc[oo][k];
                    }
                }
        }
        __syncthreads();
    }
    for (int i = tid; i < 8 * NPOS; i += 256)
        xpart[((size_t)cs * IN_CH + o0 + (i / NPOS)) * NPOS + (i % NPOS)] = redbuf[i];
}

// ---------- kernel 2: reduce split-K + bias + relu ----------
__global__ void k_reduce_relu(const float* __restrict__ xpart,
                              const float* __restrict__ b_conv,
                              float* __restrict__ xbuf) {
    const int f = blockIdx.x * blockDim.x + threadIdx.x;
    if (f >= IN_CH * NPOS) return;
    const int o = f / NPOS;
    float s = b_conv[o];
#pragma unroll
    for (int cs = 0; cs < CSPLIT; cs++) s += xpart[(size_t)cs * IN_CH * NPOS + f];
    xbuf[f] = fmaxf(s, 0.f);
}

// ---------- kernel 3: 1x1 heads, split-C partials ----------
__global__ __launch_bounds__(256) void k_heads(const float* __restrict__ xbuf,
                                               const float* __restrict__ w_cls,
                                               const float* __restrict__ w_reg,
                                               float* __restrict__ hpart) {
    const int ch = blockIdx.x % 45;
    const int q  = blockIdx.x / 45;
    const int p  = threadIdx.x;
    if (p >= NPOS) return;
    const float* w = (ch < NA) ? (w_cls + (size_t)ch * IN_CH)
                               : (w_reg + (size_t)(ch - NA) * IN_CH);
    float acc = 0.f;
    const int c0 = q * HCC;
#pragma unroll 8
    for (int c = c0; c < c0 + HCC; c++) acc += xbuf[(size_t)c * NPOS + p] * w[c];
    hpart[((size_t)q * 45 + ch) * NPOS + p] = acc;
}

// ---------- kernel 4: fused keys + exact top-1000, partitioned rank ----------
// grid = 28 blocks x 256 (4 waves). Rank is a sum over disjoint j-ranges:
// wave w ranks the block's 64 candidates over its 441-slice — 4x shorter
// serial LDS chain, same total LDS-pipe work, latency hidden across waves.
__global__ __launch_bounds__(256) void k_select(const float* __restrict__ hpart,
                                                const float* __restrict__ b_cls,
                                                const float* __restrict__ b_reg,
                                                float* __restrict__ boxes1000,
                                                float* __restrict__ scores1000,
                                                unsigned* __restrict__ invalid) {
    __shared__ ull ks[NANCH];        // 14,112 B
    __shared__ int prank[4][64];
    const int tid = threadIdx.x;
    const int wv = tid >> 6, lane = tid & 63;

    for (int it = 0; it < 7; it++) {
        const int i = it * 256 + tid;
        if (i < NANCH) {
            const int p = i / NA, a = i % NA;
            float sc = b_cls[a];
#pragma unroll
            for (int q = 0; q < HQ; q++)
                sc += hpart[(size_t)q * 45 * NPOS + (size_t)a * NPOS + p];
            const float prob = 1.0f / (1.0f + expf(-sc));
            ks[i] = ((ull)(__float_as_uint(prob) | 0x80000000u) << 32)
                  | (ull)(0xFFFFFFFFu - (unsigned)i);
        }
    }
    __syncthreads();

    const int cand = blockIdx.x * 64 + lane;
    const ull ki = (cand < NANCH) ? ks[cand] : 0ull;
    int pr = 0;
    const int j0 = wv * 441;
#pragma unroll 7
    for (int j = j0; j < j0 + 441; j++) pr += (ks[j] > ki) ? 1 : 0;
    prank[wv][lane] = pr;
    __syncthreads();

    if (wv == 0 && cand < NANCH) {
        const int rank = prank[0][lane] + prank[1][lane] + prank[2][lane] + prank[3][lane];
        if (rank < K1) {
            const int p = cand / NA, a = cand % NA;
            const int yy = p / FW, xx = p % FW;
            const int r = a / 3, s = a % 3;
            const float scv = (s == 0) ? 128.f : ((s == 1) ? 256.f : 512.f);
            const float rat = (r == 0) ? 0.5f : ((r == 1) ? 1.0f : 2.0f);
            const float hr = sqrtf(rat), wr = 1.0f / hr;
            const float wsv = wr * scv, hsv = hr * scv;
            const float sxf = (float)(xx * 16), syf = (float)(yy * 16);
            const float ax0 = sxf + rintf(-0.5f * wsv);
            const float ay0 = syf + rintf(-0.5f * hsv);
            const float ax1 = sxf + rintf(0.5f * wsv);
            const float ay1 = syf + rintf(0.5f * hsv);
            const float w = ax1 - ax0, h = ay1 - ay0;
            const float cx = ax0 + 0.5f * w, cy = ay0 + 0.5f * h;
            const int rc0 = NA + (a * 4 + 0), rc1 = NA + (a * 4 + 1);
            const int rc2 = NA + (a * 4 + 2), rc3 = NA + (a * 4 + 3);
            float dx = b_reg[a * 4 + 0], dy = b_reg[a * 4 + 1];
            float dwv = b_reg[a * 4 + 2], dhv = b_reg[a * 4 + 3];
#pragma unroll
            for (int q = 0; q < HQ; q++) {
                const size_t base = (size_t)q * 45 * NPOS;
                dx  += hpart[base + (size_t)rc0 * NPOS + p];
                dy  += hpart[base + (size_t)rc1 * NPOS + p];
                dwv += hpart[base + (size_t)rc2 * NPOS + p];
                dhv += hpart[base + (size_t)rc3 * NPOS + p];
            }
            const float dw = fminf(dwv, BBOX_CLIP);
            const float dh = fminf(dhv, BBOX_CLIP);
            const float pcx = dx * w + cx, pcy = dy * h + cy;
            const float pw = expf(dw) * w, ph = expf(dh) * h;
            const float b0 = fminf(fmaxf(pcx - 0.5f * pw, 0.f), IMG_W);
            const float b1 = fminf(fmaxf(pcy - 0.5f * ph, 0.f), IMG_H);
            const float b2 = fminf(fmaxf(pcx + 0.5f * pw, 0.f), IMG_W);
            const float b3 = fminf(fmaxf(pcy + 0.5f * ph, 0.f), IMG_H);
            boxes1000[rank * 4 + 0] = b0; boxes1000[rank * 4 + 1] = b1;
            boxes1000[rank * 4 + 2] = b2; boxes1000[rank * 4 + 3] = b3;
            scores1000[rank] = __uint_as_float((unsigned)(ki >> 32) & 0x7FFFFFFFu);
            const float bw = b2 - b0, bh = b3 - b1;
            invalid[rank] = (bw >= 16.f && bh >= 16.f) ? 0u : 1u;
        }
    }
}

// ---------- kernel 5: IoU suppression bitmask (+ compact diag array) ----------
__global__ __launch_bounds__(1024) void k_iou_mask(const float* __restrict__ boxes1000,
                                                   ull* __restrict__ mask,
                                                   ull* __restrict__ diag1000) {
    const int i = blockIdx.x;
    const int j = threadIdx.x;
    const float ix0 = boxes1000[i * 4 + 0], iy0 = boxes1000[i * 4 + 1];
    const float ix1 = boxes1000[i * 4 + 2], iy1 = boxes1000[i * 4 + 3];
    const float areai = (ix1 - ix0) * (iy1 - iy0);
    bool pred = false;
    if (j < K1 && j > i) {
        const float jx0 = boxes1000[j * 4 + 0], jy0 = boxes1000[j * 4 + 1];
        const float jx1 = boxes1000[j * 4 + 2], jy1 = boxes1000[j * 4 + 3];
        const float areaj = (jx1 - jx0) * (jy1 - jy0);
        const float xx0 = fmaxf(ix0, jx0), yy0 = fmaxf(iy0, jy0);
        const float xx1 = fminf(ix1, jx1), yy1 = fminf(iy1, jy1);
        const float w = fmaxf(xx1 - xx0, 0.f), h = fmaxf(yy1 - yy0, 0.f);
        const float inter = w * h;
        const float uni = areai + areaj - inter;
        const float iou = (uni > 0.f) ? inter / uni : 0.f;
        pred = iou > 0.7f;
    }
    const ull m = __ballot(pred);
    if ((j & 63) == 0) {
        mask[(size_t)i * 16 + (j >> 6)] = m;
        if ((j >> 6) == (i >> 6)) diag1000[i] = m;
    }
}

// ---------- kernel 6: NMS scan — ONE wave, zero barriers, zero LDS ----------
// Round-9 lesson: 32 __syncthreads (each draining vmcnt) + 15x16 shfl_xor
// butterflies made the 16-wave version ~48 us. Now everything lives in one
// wave's registers: diag rows in dval[16] (lane l holds rows r*64+l), the
// serial chain reads db via v_readlane (register->SGPR, indices fold after
// full unroll), remv update is 64 exec-masked unconditional loads + select-OR
// per block. No barriers, no LDS, no shuffles-in-chain.
__global__ __launch_bounds__(64) void k_scan(const ull* __restrict__ mask,
                                             const ull* __restrict__ diag1000,
                                             const unsigned* __restrict__ invalid,
                                             ull* __restrict__ remw_g) {
    const int lane = threadIdx.x;

    // init removal words from invalid[] (lane w holds word w)
    ull remv = 0ull;
#pragma unroll
    for (int w = 0; w < 16; w++) {
        const int idx = w * 64 + lane;
        const bool iv = (idx < K1) && (invalid[(idx < K1) ? idx : (K1 - 1)] & 1u);
        const ull bl = __ballot(iv);
        remv = (lane == w) ? bl : remv;
    }

    // diag preload: lane l holds diag row r*64+l in dval[r]
    ull dval[16];
#pragma unroll
    for (int r = 0; r < 16; r++) {
        const int idx = r * 64 + lane;
        dval[r] = diag1000[(idx < K1) ? idx : (K1 - 1)];
    }

#pragma unroll
    for (int w = 0; w < 16; w++) {
        const int bbase = w * 64;
        ull cur = readlane_u64(remv, w);
        ull kept = 0ull;
#pragma unroll
        for (int b = 0; b < 64; b++) {
            const ull db = readlane_u64(dval[w], b);
            const bool kb = (bbase + b < K1) && (((cur >> b) & 1ull) == 0ull);
            cur  |= kb ? db : 0ull;
            kept |= kb ? (1ull << b) : 0ull;
        }
        if (lane < 16) {
            const ull* mrow = mask + (size_t)bbase * 16 + lane;
#pragma unroll 16
            for (int b = 0; b < 64; b++) {
                const ull mv = mrow[(size_t)(((bbase + b) < K1) ? b : 0) * 16];
                remv |= ((kept >> b) & 1ull) ? mv : 0ull;
            }
        }
    }
    if (lane < 16) remw_g[lane] = remv;
}

// ---------- kernel 7: masked top-300, partitioned rank + output ----------
// grid = 16 blocks x 256 (4 waves): wave w ranks the block's 64 candidates
// over its 250-slice; partial ranks summed in LDS.
__global__ __launch_bounds__(256) void k_out(const ull* __restrict__ remw_g,
                                             const float* __restrict__ scores1000,
                                             const float* __restrict__ boxes1000,
                                             float* __restrict__ out) {
    __shared__ ull ks[1024];
    __shared__ int prank[4][64];
    const int tid = threadIdx.x;
    const int wv = tid >> 6, lane = tid & 63;

    for (int it = 0; it < 4; it++) {
        const int t = it * 256 + tid;
        const ull w = remw_g[t >> 6];                      // uniform s_load
        ull k = 0ull;
        if (t < K1) {
            const bool rem = (w >> (t & 63)) & 1ull;
            const float m = rem ? -1.0f : scores1000[t];
            k = ((ull)f2sort(m) << 32) | (ull)(0xFFFFFFFFu - (unsigned)t);
        }
        ks[t] = k;
    }
    __syncthreads();

    const int cand = blockIdx.x * 64 + lane;
    const ull kj = (cand < K1) ? ks[cand] : 0ull;
    int pr = 0;
    const int j0 = wv * 250;
#pragma unroll 10
    for (int j = j0; j < j0 + 250; j++) pr += (ks[j] > kj) ? 1 : 0;
    prank[wv][lane] = pr;
    __syncthreads();

    if (wv == 0 && cand < K1) {
        const int rank = prank[0][lane] + prank[1][lane] + prank[2][lane] + prank[3][lane];
        if (rank < TOPK_N) {
            const float sc = sort2f((unsigned)(kj >> 32));
            const unsigned b = 0xFFFFFFFFu - (unsigned)(kj & 0xFFFFFFFFull);
            float o0 = 0.f, o1 = 0.f, o2 = 0.f, o3 = 0.f, os = 0.f;
            if (sc > 0.f) {
                o0 = boxes1000[b * 4 + 0]; o1 = boxes1000[b * 4 + 1];
                o2 = boxes1000[b * 4 + 2]; o3 = boxes1000[b * 4 + 3];
                os = sc;
            }
            out[rank * 4 + 0] = o0; out[rank * 4 + 1] = o1;
            out[rank * 4 + 2] = o2; out[rank * 4 + 3] = o3;
            out[1200 + rank] = os;
        }
    }
}

// ---------- launcher ----------
extern "C" void kernel_launch(void* const* d_in, const int* in_sizes, int n_in,
                              void* d_out, int out_size, void* d_ws, size_t ws_size,
                              hipStream_t stream) {
    const float* feature = (const float*)d_in[1];
    const float* w_conv  = (const float*)d_in[2];
    const float* b_conv  = (const float*)d_in[3];
    const float* w_cls   = (const float*)d_in[4];
    const float* b_cls   = (const float*)d_in[5];
    const float* w_reg   = (const float*)d_in[6];
    const float* b_reg   = (const float*)d_in[7];
    float* out = (float*)d_out;

    char* w = (char*)d_ws;
    float*    pad     = (float*)(w + 0);             //   786,432 B
    float*    xpart   = (float*)(w + 786432);        // 9,633,792 B -> 10,420,224
    float*    xbuf    = (float*)(w + 10420224);      //   602,112 B -> 11,022,336
    float*    hpart   = (float*)(w + 11022336);      //   282,240 B -> 11,304,576
    float*    boxes   = (float*)(w + 11304576);      //    16,000 B -> 11,320,576
    float*    scrs    = (float*)(w + 11320576);      //     4,000 B -> 11,324,576
    unsigned* inval   = (unsigned*)(w + 11324576);   //     4,000 B -> 11,328,576
    ull*      mask    = (ull*)  (w + 11328576);      //   128,000 B -> 11,456,576
    ull*      diag    = (ull*)  (w + 11456576);      //     8,000 B -> 11,464,576
    ull*      remw    = (ull*)  (w + 11464576);      //       128 B -> 11,464,704

    k_pad<<<IN_CH, 256, 0, stream>>>(feature, pad);
    k_conv<<<96 * CSPLIT, 256, 0, stream>>>(pad, w_conv, xpart);
    k_reduce_relu<<<(IN_CH * NPOS + 255) / 256, 256, 0, stream>>>(xpart, b_conv, xbuf);
    k_heads<<<45 * HQ, 256, 0, stream>>>(xbuf, w_cls, w_reg, hpart);
    k_select<<<28, 256, 0, stream>>>(hpart, b_cls, b_reg, boxes, scrs, inval);
    k_iou_mask<<<K1, 1024, 0, stream>>>(boxes, mask, diag);
    k_scan<<<1, 64, 0, stream>>>(mask, diag, inval, remw);
    k_out<<<16, 256, 0, stream>>>(remw, scrs, boxes, out);
}

// Round 11
// 193.384 us; speedup vs baseline: 1.9212x; 1.9212x over previous
//
#include <hip/hip_runtime.h>
#include <cstdint>
#include <cstddef>

#define IN_CH 768
#define FH 14
#define FW 14
#define NPOS 196         // 14*14
#define NA 9
#define NANCH 1764       // 196*9
#define K1 1000
#define TOPK_N 300
#define CSPLIT 16
#define CPBLK (IN_CH / CSPLIT)  // 48 channels per block
#define WCH (CPBLK / 4)         // 12 channels per wave
#define HQ 8                    // heads split-C chunks
#define HCC (IN_CH / HQ)        // 96 channels per chunk
#define BBOX_CLIP 4.135166556742356f
#define IMG_W 224.0f
#define IMG_H 224.0f

typedef unsigned long long ull;

// ---------- helpers ----------
__device__ __forceinline__ uint32_t f2sort(float f) {
    uint32_t b = __float_as_uint(f);
    return (b & 0x80000000u) ? ~b : (b | 0x80000000u);
}
__device__ __forceinline__ float sort2f(uint32_t s) {
    uint32_t b = (s & 0x80000000u) ? (s & 0x7fffffffu) : ~s;
    return __uint_as_float(b);
}
__device__ __forceinline__ ull readlane_u64(ull v, int l) {
    unsigned lo = __builtin_amdgcn_readlane((unsigned)(v & 0xffffffffull), l);
    unsigned hi = __builtin_amdgcn_readlane((unsigned)(v >> 32), l);
    return ((ull)hi << 32) | (ull)lo;
}

// ---------- kernel 0: zero-padded 16x16 feature planes ----------
__global__ __launch_bounds__(256) void k_pad(const float* __restrict__ feature,
                                             float* __restrict__ pad) {
    const int c = blockIdx.x, t = threadIdx.x;
    const int row = t >> 4, col = t & 15;
    const bool in = (row >= 1 && row <= 14 && col >= 1 && col <= 14);
    pad[(size_t)c * 256 + t] = in ? feature[IN_CH + (size_t)c * NPOS + (row - 1) * FW + (col - 1)] : 0.f;
}

// ---------- kernel 1: 3x3 conv, 1x4 strips, aligned vector taps ----------
__global__ __launch_bounds__(256) void k_conv(const float* __restrict__ pad,
                                              const float* __restrict__ w_conv,
                                              float* __restrict__ xpart) {
    __shared__ float wlds[CPBLK * 8 * 12];   // 18,432 B
    __shared__ float redbuf[8 * NPOS];       // 6,272 B
    const int tid  = threadIdx.x;
    const int wv   = tid >> 6, lane = tid & 63;
    const int cs   = blockIdx.x & (CSPLIT - 1);
    const int ob   = blockIdx.x / CSPLIT;
    const int o0   = ob * 8;

    for (int i = tid; i < CPBLK * 8 * 9; i += 256) {
        const int oo = i / (CPBLK * 9);
        const int r  = i % (CPBLK * 9);
        const int cc = r / 9, k = r % 9;
        wlds[(cc * 8 + oo) * 12 + k] =
            w_conv[((size_t)(o0 + oo) * IN_CH + (cs * CPBLK + cc)) * 9 + k];
    }

    const int row = lane >> 2, s4 = (lane & 3) * 4;
    const bool act = (row < FH);
    const int rr = act ? row : 0;

    const int cbase = cs * CPBLK + wv * WCH;
    const float* base = pad + (size_t)cbase * 256 + rr * 16 + s4;

    float acc[8][4];
#pragma unroll
    for (int oo = 0; oo < 8; oo++)
#pragma unroll
        for (int q = 0; q < 4; q++) acc[oo][q] = 0.f;

    float t[3][6];
#pragma unroll
    for (int rI = 0; rI < 3; rI++) {
        const float4 a = *(const float4*)(base + rI * 16);
        const float2 b = *(const float2*)(base + rI * 16 + 4);
        t[rI][0] = a.x; t[rI][1] = a.y; t[rI][2] = a.z; t[rI][3] = a.w;
        t[rI][4] = b.x; t[rI][5] = b.y;
    }

    __syncthreads();   // weights staged

    for (int cc = 0; cc < WCH; cc++) {
        float tn[3][6];
        if (cc + 1 < WCH) {
            const float* nb = base + (size_t)(cc + 1) * 256;
#pragma unroll
            for (int rI = 0; rI < 3; rI++) {
                const float4 a = *(const float4*)(nb + rI * 16);
                const float2 b = *(const float2*)(nb + rI * 16 + 4);
                tn[rI][0] = a.x; tn[rI][1] = a.y; tn[rI][2] = a.z; tn[rI][3] = a.w;
                tn[rI][4] = b.x; tn[rI][5] = b.y;
            }
        }
        const int cib = wv * WCH + cc;
#pragma unroll
        for (int oo = 0; oo < 8; oo++) {
            const int off = (cib * 8 + oo) * 12;
            const float4 wA = *(const float4*)&wlds[off];
            const float4 wB = *(const float4*)&wlds[off + 4];
            const float  w8 = wlds[off + 8];
#pragma unroll
            for (int k = 0; k < 4; k++) {
                acc[oo][k] += t[0][k] * wA.x + t[0][k + 1] * wA.y + t[0][k + 2] * wA.z
                            + t[1][k] * wA.w + t[1][k + 1] * wB.x + t[1][k + 2] * wB.y
                            + t[2][k] * wB.z + t[2][k + 1] * wB.w + t[2][k + 2] * w8;
            }
        }
        if (cc + 1 < WCH) {
#pragma unroll
            for (int rI = 0; rI < 3; rI++)
#pragma unroll
                for (int j = 0; j < 6; j++) t[rI][j] = tn[rI][j];
        }
    }

    __syncthreads();
    for (int w = 0; w < 4; w++) {
        if (wv == w && act) {
#pragma unroll
            for (int oo = 0; oo < 8; oo++)
#pragma unroll
                for (int k = 0; k < 4; k++) {
                    const int cx = s4 + k;
                    if (cx < FW) {
                        const int p = row * FW + cx;
                        if (w == 0) redbuf[oo * NPOS + p] = acc[oo][k];
                        else        redbuf[oo * NPOS + p] += acc[oo][k];
                    }
                }
        }
        __syncthreads();
    }
    for (int i = tid; i < 8 * NPOS; i += 256)
        xpart[((size_t)cs * IN_CH + o0 + (i / NPOS)) * NPOS + (i % NPOS)] = redbuf[i];
}

// ---------- kernel 2: reduce split-K + bias + relu ----------
__global__ void k_reduce_relu(const float* __restrict__ xpart,
                              const float* __restrict__ b_conv,
                              float* __restrict__ xbuf) {
    const int f = blockIdx.x * blockDim.x + threadIdx.x;
    if (f >= IN_CH * NPOS) return;
    const int o = f / NPOS;
    float s = b_conv[o];
#pragma unroll
    for (int cs = 0; cs < CSPLIT; cs++) s += xpart[(size_t)cs * IN_CH * NPOS + f];
    xbuf[f] = fmaxf(s, 0.f);
}

// ---------- kernel 3: 1x1 heads, split-C partials ----------
__global__ __launch_bounds__(256) void k_heads(const float* __restrict__ xbuf,
                                               const float* __restrict__ w_cls,
                                               const float* __restrict__ w_reg,
                                               float* __restrict__ hpart) {
    const int ch = blockIdx.x % 45;
    const int q  = blockIdx.x / 45;
    const int p  = threadIdx.x;
    if (p >= NPOS) return;
    const float* w = (ch < NA) ? (w_cls + (size_t)ch * IN_CH)
                               : (w_reg + (size_t)(ch - NA) * IN_CH);
    float acc = 0.f;
    const int c0 = q * HCC;
#pragma unroll 8
    for (int c = c0; c < c0 + HCC; c++) acc += xbuf[(size_t)c * NPOS + p] * w[c];
    hpart[((size_t)q * 45 + ch) * NPOS + p] = acc;
}

// ---------- kernel 4: fused keys + exact top-1000, partitioned rank ----------
__global__ __launch_bounds__(256) void k_select(const float* __restrict__ hpart,
                                                const float* __restrict__ b_cls,
                                                const float* __restrict__ b_reg,
                                                float* __restrict__ boxes1000,
                                                float* __restrict__ scores1000,
                                                unsigned* __restrict__ invalid) {
    __shared__ ull ks[NANCH];        // 14,112 B
    __shared__ int prank[4][64];
    const int tid = threadIdx.x;
    const int wv = tid >> 6, lane = tid & 63;

    for (int it = 0; it < 7; it++) {
        const int i = it * 256 + tid;
        if (i < NANCH) {
            const int p = i / NA, a = i % NA;
            float sc = b_cls[a];
#pragma unroll
            for (int q = 0; q < HQ; q++)
                sc += hpart[(size_t)q * 45 * NPOS + (size_t)a * NPOS + p];
            const float prob = 1.0f / (1.0f + expf(-sc));
            ks[i] = ((ull)(__float_as_uint(prob) | 0x80000000u) << 32)
                  | (ull)(0xFFFFFFFFu - (unsigned)i);
        }
    }
    __syncthreads();

    const int cand = blockIdx.x * 64 + lane;
    const ull ki = (cand < NANCH) ? ks[cand] : 0ull;
    int pr = 0;
    const int j0 = wv * 441;
#pragma unroll 7
    for (int j = j0; j < j0 + 441; j++) pr += (ks[j] > ki) ? 1 : 0;
    prank[wv][lane] = pr;
    __syncthreads();

    if (wv == 0 && cand < NANCH) {
        const int rank = prank[0][lane] + prank[1][lane] + prank[2][lane] + prank[3][lane];
        if (rank < K1) {
            const int p = cand / NA, a = cand % NA;
            const int yy = p / FW, xx = p % FW;
            const int r = a / 3, s = a % 3;
            const float scv = (s == 0) ? 128.f : ((s == 1) ? 256.f : 512.f);
            const float rat = (r == 0) ? 0.5f : ((r == 1) ? 1.0f : 2.0f);
            const float hr = sqrtf(rat), wr = 1.0f / hr;
            const float wsv = wr * scv, hsv = hr * scv;
            const float sxf = (float)(xx * 16), syf = (float)(yy * 16);
            const float ax0 = sxf + rintf(-0.5f * wsv);
            const float ay0 = syf + rintf(-0.5f * hsv);
            const float ax1 = sxf + rintf(0.5f * wsv);
            const float ay1 = syf + rintf(0.5f * hsv);
            const float w = ax1 - ax0, h = ay1 - ay0;
            const float cx = ax0 + 0.5f * w, cy = ay0 + 0.5f * h;
            const int rc0 = NA + (a * 4 + 0), rc1 = NA + (a * 4 + 1);
            const int rc2 = NA + (a * 4 + 2), rc3 = NA + (a * 4 + 3);
            float dx = b_reg[a * 4 + 0], dy = b_reg[a * 4 + 1];
            float dwv = b_reg[a * 4 + 2], dhv = b_reg[a * 4 + 3];
#pragma unroll
            for (int q = 0; q < HQ; q++) {
                const size_t base = (size_t)q * 45 * NPOS;
                dx  += hpart[base + (size_t)rc0 * NPOS + p];
                dy  += hpart[base + (size_t)rc1 * NPOS + p];
                dwv += hpart[base + (size_t)rc2 * NPOS + p];
                dhv += hpart[base + (size_t)rc3 * NPOS + p];
            }
            const float dw = fminf(dwv, BBOX_CLIP);
            const float dh = fminf(dhv, BBOX_CLIP);
            const float pcx = dx * w + cx, pcy = dy * h + cy;
            const float pw = expf(dw) * w, ph = expf(dh) * h;
            const float b0 = fminf(fmaxf(pcx - 0.5f * pw, 0.f), IMG_W);
            const float b1 = fminf(fmaxf(pcy - 0.5f * ph, 0.f), IMG_H);
            const float b2 = fminf(fmaxf(pcx + 0.5f * pw, 0.f), IMG_W);
            const float b3 = fminf(fmaxf(pcy + 0.5f * ph, 0.f), IMG_H);
            boxes1000[rank * 4 + 0] = b0; boxes1000[rank * 4 + 1] = b1;
            boxes1000[rank * 4 + 2] = b2; boxes1000[rank * 4 + 3] = b3;
            scores1000[rank] = __uint_as_float((unsigned)(ki >> 32) & 0x7FFFFFFFu);
            const float bw = b2 - b0, bh = b3 - b1;
            invalid[rank] = (bw >= 16.f && bh >= 16.f) ? 0u : 1u;
        }
    }
}

// ---------- kernel 5: IoU suppression bitmask ----------
__global__ __launch_bounds__(1024) void k_iou_mask(const float* __restrict__ boxes1000,
                                                   ull* __restrict__ mask) {
    const int i = blockIdx.x;
    const int j = threadIdx.x;
    const float ix0 = boxes1000[i * 4 + 0], iy0 = boxes1000[i * 4 + 1];
    const float ix1 = boxes1000[i * 4 + 2], iy1 = boxes1000[i * 4 + 3];
    const float areai = (ix1 - ix0) * (iy1 - iy0);
    bool pred = false;
    if (j < K1 && j > i) {
        const float jx0 = boxes1000[j * 4 + 0], jy0 = boxes1000[j * 4 + 1];
        const float jx1 = boxes1000[j * 4 + 2], jy1 = boxes1000[j * 4 + 3];
        const float areaj = (jx1 - jx0) * (jy1 - jy0);
        const float xx0 = fmaxf(ix0, jx0), yy0 = fmaxf(iy0, jy0);
        const float xx1 = fminf(ix1, jx1), yy1 = fminf(iy1, jy1);
        const float w = fmaxf(xx1 - xx0, 0.f), h = fmaxf(yy1 - yy0, 0.f);
        const float inter = w * h;
        const float uni = areai + areaj - inter;
        const float iou = (uni > 0.f) ? inter / uni : 0.f;
        pred = iou > 0.7f;
    }
    const ull m = __ballot(pred);
    if ((j & 63) == 0) mask[(size_t)i * 16 + (j >> 6)] = m;
}

// ---------- kernel 6: NMS scan — column-pipelined, ONE wave ----------
// Round-10 lesson: kept-dependent loads behind the chain serialize at ~500
// cyc each when the allocator can't batch them. Here NOTHING behind the chain
// touches memory: block w only needs mask COLUMN w (static addresses),
// double-buffered in registers one block ahead. Chain diag = col[par][w] via
// v_readlane (pure SALU chain). Contribution to word w+1 = per-lane select by
// keptpack (lane-local u32) over resident col regs + one 6-step shfl_xor
// OR-butterfly per block. No barriers, no LDS, no kept-dependent loads.
__global__ __launch_bounds__(64) void k_scan(const ull* __restrict__ mask,
                                             const unsigned* __restrict__ invalid,
                                             ull* __restrict__ remw_g) {
    const int lane = threadIdx.x;

    // pack invalid bits: bit w of invpack = invalid[w*64+lane]
    unsigned invpack = 0u;
#pragma unroll
    for (int w = 0; w < 16; w++) {
        const int idx = w * 64 + lane;
        const unsigned iv = (idx < K1) ? (invalid[idx] & 1u) : 0u;
        invpack |= iv << w;
    }

    // col[par][q] = mask[q*64+lane][current column] — double buffered
    ull col[2][16];
    col[0][0] = mask[(size_t)lane * 16 + 0];                    // column 0 (block-0 diag)
#pragma unroll
    for (int q = 0; q < 2; q++) {                               // column 1
        const int row = q * 64 + lane;
        col[1][q] = mask[(size_t)row * 16 + 1];
    }

    unsigned keptpack = 0u;
    ull cur = __ballot((invpack >> 0) & 1u);
    ull remv_store = 0ull;

#pragma unroll
    for (int w = 0; w < 16; w++) {
        const int par = w & 1;
        // serial chain: pure SALU, diag via v_readlane of resident registers
        ull kept = 0ull;
#pragma unroll
        for (int b = 0; b < 64; b++) {
            const ull db = readlane_u64(col[par][w], b);
            const bool kb = (w * 64 + b < K1) && (((cur >> b) & 1ull) == 0ull);
            cur  |= kb ? db : 0ull;
            kept |= kb ? (1ull << b) : 0ull;
        }
        remv_store = (lane == w) ? cur : remv_store;
        keptpack |= (unsigned)((kept >> lane) & 1ull) << w;

        if (w + 1 < 16) {
            const int np = par ^ 1;
            // prefetch column w+2 into freed buffer (static addresses)
            if (w + 2 < 16) {
#pragma unroll
                for (int q = 0; q < 16; q++) {
                    if (q <= w + 2) {
                        const int row = q * 64 + lane;
                        col[par][q] = mask[(size_t)((row < K1) ? row : (K1 - 1)) * 16 + (w + 2)];
                    }
                }
            }
            // contribution to word w+1 from kept rows of blocks 0..w
            ull contrib = 0ull;
#pragma unroll
            for (int q = 0; q < 16; q++) {
                if (q <= w) {
                    const bool kb = (keptpack >> q) & 1u;
                    contrib |= kb ? col[np][q] : 0ull;
                }
            }
#pragma unroll
            for (int off = 1; off < 64; off <<= 1)
                contrib |= __shfl_xor(contrib, off);
            cur = __ballot((invpack >> (w + 1)) & 1u) | readlane_u64(contrib, 0);
        }
    }
    if (lane < 16) remw_g[lane] = remv_store;
}

// ---------- kernel 7: masked top-300, partitioned rank + output ----------
__global__ __launch_bounds__(256) void k_out(const ull* __restrict__ remw_g,
                                             const float* __restrict__ scores1000,
                                             const float* __restrict__ boxes1000,
                                             float* __restrict__ out) {
    __shared__ ull ks[1024];
    __shared__ int prank[4][64];
    const int tid = threadIdx.x;
    const int wv = tid >> 6, lane = tid & 63;

    for (int it = 0; it < 4; it++) {
        const int t = it * 256 + tid;
        const ull w = remw_g[t >> 6];                      // uniform s_load
        ull k = 0ull;
        if (t < K1) {
            const bool rem = (w >> (t & 63)) & 1ull;
            const float m = rem ? -1.0f : scores1000[t];
            k = ((ull)f2sort(m) << 32) | (ull)(0xFFFFFFFFu - (unsigned)t);
        }
        ks[t] = k;
    }
    __syncthreads();

    const int cand = blockIdx.x * 64 + lane;
    const ull kj = (cand < K1) ? ks[cand] : 0ull;
    int pr = 0;
    const int j0 = wv * 250;
#pragma unroll 10
    for (int j = j0; j < j0 + 250; j++) pr += (ks[j] > kj) ? 1 : 0;
    prank[wv][lane] = pr;
    __syncthreads();

    if (wv == 0 && cand < K1) {
        const int rank = prank[0][lane] + prank[1][lane] + prank[2][lane] + prank[3][lane];
        if (rank < TOPK_N) {
            const float sc = sort2f((unsigned)(kj >> 32));
            const unsigned b = 0xFFFFFFFFu - (unsigned)(kj & 0xFFFFFFFFull);
            float o0 = 0.f, o1 = 0.f, o2 = 0.f, o3 = 0.f, os = 0.f;
            if (sc > 0.f) {
                o0 = boxes1000[b * 4 + 0]; o1 = boxes1000[b * 4 + 1];
                o2 = boxes1000[b * 4 + 2]; o3 = boxes1000[b * 4 + 3];
                os = sc;
            }
            out[rank * 4 + 0] = o0; out[rank * 4 + 1] = o1;
            out[rank * 4 + 2] = o2; out[rank * 4 + 3] = o3;
            out[1200 + rank] = os;
        }
    }
}

// ---------- launcher ----------
extern "C" void kernel_launch(void* const* d_in, const int* in_sizes, int n_in,
                              void* d_out, int out_size, void* d_ws, size_t ws_size,
                              hipStream_t stream) {
    const float* feature = (const float*)d_in[1];
    const float* w_conv  = (const float*)d_in[2];
    const float* b_conv  = (const float*)d_in[3];
    const float* w_cls   = (const float*)d_in[4];
    const float* b_cls   = (const float*)d_in[5];
    const float* w_reg   = (const float*)d_in[6];
    const float* b_reg   = (const float*)d_in[7];
    float* out = (float*)d_out;

    char* w = (char*)d_ws;
    float*    pad     = (float*)(w + 0);             //   786,432 B
    float*    xpart   = (float*)(w + 786432);        // 9,633,792 B -> 10,420,224
    float*    xbuf    = (float*)(w + 10420224);      //   602,112 B -> 11,022,336
    float*    hpart   = (float*)(w + 11022336);      //   282,240 B -> 11,304,576
    float*    boxes   = (float*)(w + 11304576);      //    16,000 B -> 11,320,576
    float*    scrs    = (float*)(w + 11320576);      //     4,000 B -> 11,324,576
    unsigned* inval   = (unsigned*)(w + 11324576);   //     4,000 B -> 11,328,576
    ull*      mask    = (ull*)  (w + 11328576);      //   128,000 B -> 11,456,576
    ull*      remw    = (ull*)  (w + 11456576);      //       128 B -> 11,456,704

    k_pad<<<IN_CH, 256, 0, stream>>>(feature, pad);
    k_conv<<<96 * CSPLIT, 256, 0, stream>>>(pad, w_conv, xpart);
    k_reduce_relu<<<(IN_CH * NPOS + 255) / 256, 256, 0, stream>>>(xpart, b_conv, xbuf);
    k_heads<<<45 * HQ, 256, 0, stream>>>(xbuf, w_cls, w_reg, hpart);
    k_select<<<28, 256, 0, stream>>>(hpart, b_cls, b_reg, boxes, scrs, inval);
    k_iou_mask<<<K1, 1024, 0, stream>>>(boxes, mask);
    k_scan<<<1, 64, 0, stream>>>(mask, inval, remw);
    k_out<<<16, 256, 0, stream>>>(remw, scrs, boxes, out);
}